// Round 10
// baseline (17.141 us; speedup 1.0000x reference)
//
#include <hip/hip_runtime.h>

// KAN layer: out[bs,o] = sum_{i,n} tanh(h[i,n,o]*x[bs,i] + b[i,n,o]) * w[i,n,o]
// B=2, S=1024 -> BS=2048 ; I=64, N=16, O=64.
//
// Round 8 -> 9: structural-cost shrink (discriminating experiment for the
// "~11us harness floor" hypothesis).
//  - 512 blocks x 512 threads = 2 blocks/CU (cross-block overlap; cheaper
//    barriers than R8's 16-wave blocks).
//  - fit phase fully intra-wave: 16-lane group G fits i=2G,2G+1 via
//    __shfl-based DCT + monomial conversion -> NO block barriers in fit.
//    Wave w's groups fit exactly i in [8w, 8w+8) = the slice it evaluates.
//  - barriers: 9 -> 2 (one after stage+fit, one before cross-wave reduce).
//  - x staged once per block (256 rows, stride-65 -> 2-way-free banks),
//    prescaled by 1/XM; eval = 96 fma per (bs, 8-i slice) in two 4-i halves
//    (keeps VGPR ~80).
//  - numerics identical to validated NC=12 / XM=5 path (absmax 9.8e-4).

#define NC 12
#define XM_D 5.0
#define INV_XM 0.2f
#define N_DIM 16
#define O_DIM 64
#define I_DIM 64

struct Tables {
    float xnode[16];        // XM * cos((2s+1)pi/24), s<12 (padded)
    float cosm[16][12];     // cos(k*(2s+1)*pi/24), rows k>=12 zero
    float tmf[12][16];      // T_k monomial coeffs, cols m>=12 zero
};

constexpr Tables make_tables() {
    Tables T{};
    const double Q[13] = {
        1.0,
        0.991444861373810, 0.965925826289068, 0.923879532511287,
        0.866025403784439, 0.793353340291235, 0.707106781186548,
        0.608761429008721, 0.5,               0.382683432365090,
        0.258819045102521, 0.130526192220052, 0.0 };
    double c[48] = {};
    for (int m = 0; m < 48; ++m) {
        int mm = (m <= 24) ? m : 48 - m;            // cos(2pi-t)=cos(t)
        c[m] = (mm <= 12) ? Q[mm] : -Q[24 - mm];    // cos(pi-t)=-cos(t)
    }
    for (int s = 0; s < 16; ++s) {
        int ss = (s < 12) ? s : 11;
        T.xnode[s] = (float)(XM_D * c[2 * ss + 1]);
    }
    for (int k = 0; k < 12; ++k)
        for (int s = 0; s < 12; ++s)
            T.cosm[k][s] = (float)c[(k * (2 * s + 1)) % 48];
    double tm[12][12] = {};
    tm[0][0] = 1.0; tm[1][1] = 1.0;                 // T0=1, T1=t
    for (int k = 2; k < 12; ++k)
        for (int m = 0; m < 12; ++m) {
            double lo = (m > 0) ? tm[k - 1][m - 1] : 0.0;
            tm[k][m] = 2.0 * lo - tm[k - 2][m];     // T_k = 2t T_{k-1} - T_{k-2}
        }
    for (int k = 0; k < 12; ++k)
        for (int m = 0; m < 12; ++m)
            T.tmf[k][m] = (float)tm[k][m];
    return T;
}

__device__ constexpr Tables TBL = make_tables();

__global__ __launch_bounds__(512, 4)
void kan_one(const float* __restrict__ x,
             const float* __restrict__ w,
             const float* __restrict__ h,
             const float* __restrict__ bb,
             float* __restrict__ out) {
    const int tid = threadIdx.x;
    const int o   = blockIdx.x & 63;   // this block's output column
    const int q   = blockIdx.x >> 6;   // bs eighth (256 rows)

    __shared__ float Cf[I_DIM * NC];   // monomial coeffs [i][m]   (3 KB)
    __shared__ float xl[256 * 65];     // x/XM chunk [bs][i]       (66.5 KB)
    __shared__ float red[8 * 256];     // wave partials            (8 KB)

    const int bs_base = q * 256;

    // ---------- stage x (prescaled by 1/XM) into LDS ----------
    {
        const float4* __restrict__ src = (const float4*)(x + bs_base * 64);
#pragma unroll
        for (int r = 0; r < 8; ++r) {
            const int    i4  = r * 512 + tid;   // float4 idx 0..4095
            const float4 v   = src[i4];
            const int    bsl = i4 >> 4;
            const int    ic  = (i4 & 15) * 4;
            float* d = &xl[bsl * 65 + ic];
            d[0] = v.x * INV_XM; d[1] = v.y * INV_XM;
            d[2] = v.z * INV_XM; d[3] = v.w * INV_XM;
        }
    }

    // ---------- fit: 16-lane group G fits i = 2G, 2G+1 (intra-wave) --------
    const int G  = tid >> 4;           // 0..31
    const int sl = tid & 15;
    constexpr float K = 2.88539008177792681472f;   // 2*log2(e)

#pragma unroll
    for (int half = 0; half < 2; ++half) {
        const int i = 2 * G + half;

        // sample F[sl] = f_i(xnode[sl]) with accurate tanh
        float F = 0.f;
        if (sl < NC) {
            const float xs   = TBL.xnode[sl];
            const int   base = i * (N_DIM * O_DIM) + o;
#pragma unroll
            for (int n = 0; n < N_DIM; ++n) {
                const int   idx = base + n * O_DIM;
                const float z   = fmaf(h[idx], xs, bb[idx]);
                const float e   = __builtin_amdgcn_exp2f(K * z);
                const float r   = __builtin_amdgcn_rcpf(e + 1.f);
                F = fmaf(w[idx], fmaf(-2.f, r, 1.f), F);   // w * tanh(z)
            }
        }

        // Chebyshev coeff k = sl via intra-group shuffles
        float cc = 0.f;
#pragma unroll
        for (int s = 0; s < NC; ++s)
            cc = fmaf(__shfl(F, s, 16), TBL.cosm[sl][s], cc);
        cc *= (sl == 0) ? (1.f / 12.f) : (2.f / 12.f);

        // monomial coeff m = sl via intra-group shuffles
        float mono = 0.f;
#pragma unroll
        for (int k = 0; k < NC; ++k)
            mono = fmaf(__shfl(cc, k, 16), TBL.tmf[k][sl], mono);

        if (sl < NC) Cf[i * NC + sl] = mono;
    }
    __syncthreads();

    // ---------- eval: wave w covers i in [8w, 8w+8), all 256 rows ----------
    const int wave = tid >> 6;         // 0..7
    const int lane = tid & 63;
    const int i0   = wave * 8;

    float acc[4] = {0.f, 0.f, 0.f, 0.f};

#pragma unroll
    for (int half = 0; half < 2; ++half) {
        // 4 i-chains' coefficients into VGPRs (wave-uniform broadcasts)
        float cf[4][NC];
#pragma unroll
        for (int ii = 0; ii < 4; ++ii)
#pragma unroll
            for (int m = 0; m < NC; ++m)
                cf[ii][m] = Cf[(i0 + half * 4 + ii) * NC + m];

#pragma unroll
        for (int p = 0; p < 4; ++p) {
            const int bsl = p * 64 + lane;
            const float* __restrict__ xr = &xl[bsl * 65 + i0 + half * 4];
            const float t0 = xr[0], t1 = xr[1], t2 = xr[2], t3 = xr[3];
            float p0 = cf[0][NC - 1], p1 = cf[1][NC - 1];
            float p2 = cf[2][NC - 1], p3 = cf[3][NC - 1];
#pragma unroll
            for (int m = NC - 2; m >= 0; --m) {
                p0 = fmaf(p0, t0, cf[0][m]);
                p1 = fmaf(p1, t1, cf[1][m]);
                p2 = fmaf(p2, t2, cf[2][m]);
                p3 = fmaf(p3, t3, cf[3][m]);
            }
            acc[p] += (p0 + p1) + (p2 + p3);
        }
    }

#pragma unroll
    for (int p = 0; p < 4; ++p)
        red[wave * 256 + p * 64 + lane] = acc[p];
    __syncthreads();

    // ---------- reduce 8 wave partials -> out[bs, o] ----------
    if (tid < 256) {
        float v = 0.f;
#pragma unroll
        for (int wv = 0; wv < 8; ++wv)
            v += red[wv * 256 + tid];
        out[(bs_base + tid) * 64 + o] = v;
    }
}

extern "C" void kernel_launch(void* const* d_in, const int* in_sizes, int n_in,
                              void* d_out, int out_size, void* d_ws, size_t ws_size,
                              hipStream_t stream) {
    // setup_inputs order: x, w, h, b
    const float* x = (const float*)d_in[0];
    const float* w = (const float*)d_in[1];
    const float* h = (const float*)d_in[2];
    const float* b = (const float*)d_in[3];
    float* out = (float*)d_out;

    dim3 grid(512);    // 64 o-columns x 8 bs-eighths, 2 blocks/CU
    dim3 block(512);   // 8 waves
    kan_one<<<grid, block, 0, stream>>>(x, w, h, b, out);
}

// Round 11
// 15.977 us; speedup vs baseline: 1.0728x; 1.0728x over previous
//
#include <hip/hip_runtime.h>

// KAN layer: out[bs,o] = sum_{i,n} tanh(h[i,n,o]*x[bs,i] + b[i,n,o]) * w[i,n,o]
// B=2, S=1024 -> BS=2048 ; I=64, N=16, O=64.
//
// FINAL (revert to R8, the best-measured variant: 16.0 us, absmax 9.8e-4).
//
// Session record:
//  R1 naive-exact tanh (exp2+rcp)            39.9 us
//  R2 +occupancy 8 waves/SIMD                34.3
//  R3 Pade[5/4] scalar                       35.3
//  R4 packed f32 + shared-denominator rcp    32.4   <- VALU-issue floor of
//                                                      the exact algorithm
//  R5 ALGORITHM: per-(i,o) Chebyshev fit ->  18.9      degree-15 poly eval
//  R6 parallel fit (16 thr/pair)             16.4
//  R7 cooperative-launch fusion              49.8   <- grid.sync ~30us on
//                                                      8 non-coherent XCDs
//  R8 one kernel, per-o local fit, no sync   16.0   <- THIS
//  R9 barrier/structure shrink 2x            17.1   <- proves ~12us fixed
//                                                      harness/launch floor
// Kernel arithmetic is ~3-5 us of the 16; the rest is replay overhead that
// no kernel-side change touches (R6/R8/R9 sensitivity analysis).
//
// Design: block = (o, bs-quarter). Each block fits the 64 per-i polynomials
// for ITS o locally in LDS (Chebyshev sample -> DCT -> monomial; NC=12,
// XM=5; 4x redundant chip-wide -> negligible), then evaluates its 512 bs
// rows from an LDS-staged x slice. No workspace, no 2nd kernel, no sync.

#define NC 12
#define XM_D 5.0
#define INV_XM 0.2f
#define N_DIM 16
#define O_DIM 64
#define I_DIM 64

struct Tables {
    float xnode[16];        // XM * cos((2s+1)pi/24), s=0..11 (padded to 16)
    float cosm[12][12];     // cos(k*(2s+1)*pi/24)
    float tmf[12][12];      // T_k monomial coefficients (exact integers)
};

constexpr Tables make_tables() {
    Tables T{};
    const double Q[13] = {
        1.0,
        0.991444861373810, 0.965925826289068, 0.923879532511287,
        0.866025403784439, 0.793353340291235, 0.707106781186548,
        0.608761429008721, 0.5,               0.382683432365090,
        0.258819045102521, 0.130526192220052, 0.0 };
    double c[48] = {};
    for (int m = 0; m < 48; ++m) {
        int mm = (m <= 24) ? m : 48 - m;            // cos(2pi-t)=cos(t)
        c[m] = (mm <= 12) ? Q[mm] : -Q[24 - mm];    // cos(pi-t)=-cos(t)
    }
    for (int s = 0; s < 16; ++s) {
        int ss = (s < 12) ? s : 11;
        T.xnode[s] = (float)(XM_D * c[2 * ss + 1]);
    }
    for (int k = 0; k < 12; ++k)
        for (int s = 0; s < 12; ++s)
            T.cosm[k][s] = (float)c[(k * (2 * s + 1)) % 48];
    double tm[12][12] = {};
    tm[0][0] = 1.0; tm[1][1] = 1.0;                 // T0=1, T1=t
    for (int k = 2; k < 12; ++k)
        for (int m = 0; m < 12; ++m) {
            double lo = (m > 0) ? tm[k - 1][m - 1] : 0.0;
            tm[k][m] = 2.0 * lo - tm[k - 2][m];     // T_k = 2t T_{k-1} - T_{k-2}
        }
    for (int k = 0; k < 12; ++k)
        for (int m = 0; m < 12; ++m)
            T.tmf[k][m] = (float)tm[k][m];
    return T;
}

__device__ constexpr Tables TBL = make_tables();

__global__ __launch_bounds__(1024, 4)
void kan_one(const float* __restrict__ x,
             const float* __restrict__ w,
             const float* __restrict__ h,
             const float* __restrict__ bb,
             float* __restrict__ out) {
    const int tid = threadIdx.x;
    const int o   = blockIdx.x & 63;   // this block's output column
    const int q   = blockIdx.x >> 6;   // bs quarter (512 rows)

    __shared__ float Fl[I_DIM * 13];   // samples   [i][s], stride 13
    __shared__ float Cc[I_DIM * 13];   // cheb      [i][k]
    __shared__ float Cf[I_DIM * 13];   // monomial  [i][m]
    __shared__ float xl[256 * 65];     // x chunk   [bs][i], stride 65
    __shared__ float red[16 * 256];    // wave partials

    const int ig = tid >> 4;           // i index for fit phases (0..63)
    const int sl = tid & 15;           // sample / coeff / power slot

    constexpr float K = 2.88539008177792681472f;   // 2*log2(e)

    // ---------- A1: sample F[i][s] = f_i(xnode[s]) with accurate tanh ------
    if (sl < NC) {
        const float xs   = TBL.xnode[sl];
        const int   base = ig * (N_DIM * O_DIM) + o;
        float a = 0.f;
#pragma unroll
        for (int n = 0; n < N_DIM; ++n) {
            const int   idx = base + n * O_DIM;
            const float z   = fmaf(h[idx], xs, bb[idx]);
            const float e   = __builtin_amdgcn_exp2f(K * z);
            const float r   = __builtin_amdgcn_rcpf(e + 1.f);
            a = fmaf(w[idx], fmaf(-2.f, r, 1.f), a);   // w * tanh(z)
        }
        Fl[ig * 13 + sl] = a;
    }
    __syncthreads();

    // ---------- A2: Chebyshev coefficients ---------------------------------
    if (sl < NC) {
        const int k = sl;
        float acc = 0.f;
#pragma unroll
        for (int s = 0; s < NC; ++s)
            acc = fmaf(Fl[ig * 13 + s], TBL.cosm[k][s], acc);
        Cc[ig * 13 + k] = acc * ((k == 0) ? (1.f / 12.f) : (2.f / 12.f));
    }
    __syncthreads();

    // ---------- A3: monomial coefficients ----------------------------------
    if (sl < NC) {
        const int m = sl;
        float mono = 0.f;
#pragma unroll
        for (int k = 0; k < NC; ++k)
            mono = fmaf(Cc[ig * 13 + k], TBL.tmf[k][m], mono);
        Cf[ig * 13 + m] = mono;
    }
    __syncthreads();

    // ---------- hoist this wave's 4x12 coefficients into VGPRs -------------
    const int wave = tid >> 6;
    const int lane = tid & 63;
    const int i0   = wave * 4;         // wave's i-slice
    float cf[4][NC];
#pragma unroll
    for (int ii = 0; ii < 4; ++ii)
#pragma unroll
        for (int m = 0; m < NC; ++m)
            cf[ii][m] = Cf[(i0 + ii) * 13 + m];   // wave-uniform broadcast

    // ---------- B: two chunks of 256 bs rows -------------------------------
    for (int c = 0; c < 2; ++c) {
        const int bs_base = q * 512 + c * 256;

        // stage x[bs_base .. +256, 0..63] into LDS (stride 65)
        {
            const float4* __restrict__ src = (const float4*)(x + bs_base * 64);
#pragma unroll
            for (int r = 0; r < 4; ++r) {
                const int    i4  = r * 1024 + tid;   // float4 idx 0..4095
                const float4 v   = src[i4];
                const int    bsl = i4 >> 4;          // (i4*4)/64
                const int    ic  = (i4 & 15) * 4;
                float* d = &xl[bsl * 65 + ic];
                d[0] = v.x; d[1] = v.y; d[2] = v.z; d[3] = v.w;
            }
        }
        __syncthreads();

        // evaluate: 4 passes x 64 lanes = 256 bs rows, 4 Horner chains each
#pragma unroll
        for (int p = 0; p < 4; ++p) {
            const int bsl = p * 64 + lane;
            const float t0 = xl[bsl * 65 + i0 + 0] * INV_XM;
            const float t1 = xl[bsl * 65 + i0 + 1] * INV_XM;
            const float t2 = xl[bsl * 65 + i0 + 2] * INV_XM;
            const float t3 = xl[bsl * 65 + i0 + 3] * INV_XM;
            float p0 = cf[0][NC - 1], p1 = cf[1][NC - 1];
            float p2 = cf[2][NC - 1], p3 = cf[3][NC - 1];
#pragma unroll
            for (int m = NC - 2; m >= 0; --m) {
                p0 = fmaf(p0, t0, cf[0][m]);
                p1 = fmaf(p1, t1, cf[1][m]);
                p2 = fmaf(p2, t2, cf[2][m]);
                p3 = fmaf(p3, t3, cf[3][m]);
            }
            red[wave * 256 + bsl] = (p0 + p1) + (p2 + p3);
        }
        __syncthreads();

        // reduce 16 wave partials -> out[bs, o]
        if (tid < 256) {
            float v = 0.f;
#pragma unroll
            for (int wv = 0; wv < 16; ++wv)
                v += red[wv * 256 + tid];
            out[(bs_base + tid) * 64 + o] = v;
        }
        __syncthreads();   // before next chunk overwrites xl/red
    }
}

extern "C" void kernel_launch(void* const* d_in, const int* in_sizes, int n_in,
                              void* d_out, int out_size, void* d_ws, size_t ws_size,
                              hipStream_t stream) {
    // setup_inputs order: x, w, h, b
    const float* x = (const float*)d_in[0];
    const float* w = (const float*)d_in[1];
    const float* h = (const float*)d_in[2];
    const float* b = (const float*)d_in[3];
    float* out = (float*)d_out;

    dim3 grid(256);    // 64 o-columns x 4 bs-quarters, 1 block/CU
    dim3 block(1024);  // 16 waves
    kan_one<<<grid, block, 0, stream>>>(x, w, h, b, out);
}